// Round 5
// baseline (271.175 us; speedup 1.0000x reference)
//
#include <hip/hip_runtime.h>
#include <cstdint>
#include <cstddef>

#define T_TOK 2048
#define DMODEL 1024
#define NEXP 8
#define HID 2048
#define DUMP_ID 4096   // assignment-id for padding rows (token row 2048 = zeros)

typedef __bf16 bf16x8 __attribute__((ext_vector_type(8)));
typedef float f32x4 __attribute__((ext_vector_type(4)));
typedef unsigned short u16;
typedef u16 u16x8 __attribute__((ext_vector_type(8)));

__device__ __forceinline__ u16 f2bf(float f) {
    union { float f; unsigned int u; } v; v.f = f;
    unsigned int u = v.u;
    unsigned int r = (u + 0x7FFFu + ((u >> 16) & 1u)) >> 16;  // RNE
    return (u16)r;
}

__device__ __forceinline__ void gl2lds16(const void* g, void* l) {
    __builtin_amdgcn_global_load_lds(
        (const __attribute__((address_space(1))) void*)g,
        (__attribute__((address_space(3))) void*)l,
        16, 0, 0);
}

// ------------------------------------------------------------ fused_pre -----
// blocks [0, 256)  : router scores (one wave = 2 tokens, NO atomics) + x->bf16
// block  256       : zero xb dump row
__global__ __launch_bounds__(256) void fused_pre(
    const float4* __restrict__ x4, const float4* __restrict__ gw4,
    const float* __restrict__ bias, ushort4* __restrict__ xb4,
    unsigned int* __restrict__ selpack, float* __restrict__ w2,
    unsigned int* __restrict__ xb_dump_row_u32) {
    const int b = blockIdx.x;
    const int tid = threadIdx.x;

    if (b == 256) {                          // ---- zero dump token row ----
        if (tid < DMODEL / 2) xb_dump_row_u32[tid] = 0;
        return;
    }
    // ---- router: wave wv of router-block b handles tokens 2p, 2p+1 ----
    const int wv = tid >> 6;
    const int lane = tid & 63;
    const int pair = b * 4 + wv;             // 0..1023
    const int t0 = 2 * pair, t1 = t0 + 1;

    float acc0[NEXP], acc1[NEXP];
#pragma unroll
    for (int e = 0; e < NEXP; ++e) { acc0[e] = 0.f; acc1[e] = 0.f; }
#pragma unroll
    for (int j = 0; j < 4; ++j) {
        int i4 = lane + j * 64;              // float4 index within row (256/row)
        float4 a0 = x4[t0 * 256 + i4];
        float4 a1 = x4[t1 * 256 + i4];
        ushort4 s0, s1;
        s0.x = f2bf(a0.x); s0.y = f2bf(a0.y); s0.z = f2bf(a0.z); s0.w = f2bf(a0.w);
        s1.x = f2bf(a1.x); s1.y = f2bf(a1.y); s1.z = f2bf(a1.z); s1.w = f2bf(a1.w);
        xb4[t0 * 256 + i4] = s0;
        xb4[t1 * 256 + i4] = s1;
#pragma unroll
        for (int e = 0; e < NEXP; ++e) {
            float4 g = gw4[e * 256 + i4];
            acc0[e] += a0.x * g.x + a0.y * g.y + a0.z * g.z + a0.w * g.w;
            acc1[e] += a1.x * g.x + a1.y * g.y + a1.z * g.z + a1.w * g.w;
        }
    }
#pragma unroll
    for (int e = 0; e < NEXP; ++e)
        for (int off = 32; off > 0; off >>= 1) {
            acc0[e] += __shfl_xor(acc0[e], off, 64);
            acc1[e] += __shfl_xor(acc1[e], off, 64);
        }
    if (lane == 0) {
#pragma unroll
        for (int tt = 0; tt < 2; ++tt) {
            int t = tt ? t1 : t0;
            float sc[NEXP], bi[NEXP];
#pragma unroll
            for (int e = 0; e < NEXP; ++e) {
                float a = tt ? acc1[e] : acc0[e];
                sc[e] = 1.f / (1.f + expf(-a));
                bi[e] = sc[e] + bias[e];
            }
            int e0 = 0;
            for (int e = 1; e < NEXP; ++e) if (bi[e] > bi[e0]) e0 = e;  // ties->lowest
            int e1 = -1;
            for (int e = 0; e < NEXP; ++e) {
                if (e == e0) continue;
                if (e1 < 0 || bi[e] > bi[e1]) e1 = e;
            }
            selpack[t] = (unsigned int)e0 | ((unsigned int)e1 << 8);
            w2[2 * t]     = sc[e0] * sc[e0];
            w2[2 * t + 1] = sc[e1] * sc[e1];
        }
    }
}

// ------------------------------------------------------------ build_lists ---
// 8 blocks (one per expert), 256 threads: deterministic ballot-compaction.
__global__ __launch_bounds__(256) void build_lists(
    const unsigned int* __restrict__ selpack, int* __restrict__ counts,
    int* __restrict__ list) {
    const int e = blockIdx.x;
    const int tid = threadIdx.x;
    const int lane = tid & 63;
    const int wv = tid >> 6;
    __shared__ int wsum[4];
    __shared__ int base;
    if (tid == 0) base = 0;
    __syncthreads();
    for (int tb = 0; tb < T_TOK; tb += 256) {
        int t = tb + tid;
        unsigned int sp = selpack[t];
        bool f1 = ((sp >> 8) & 255u) == (unsigned)e;
        bool f = ((sp & 255u) == (unsigned)e) | f1;
        int id = 2 * t + (f1 ? 1 : 0);
        unsigned long long m = __ballot(f);
        int pos = __popcll(m & ((1ull << lane) - 1ull));
        if (lane == 0) wsum[wv] = __popcll(m);
        __syncthreads();
        int woff = 0;
#pragma unroll
        for (int i = 0; i < 4; ++i) if (i < wv) woff += wsum[i];
        int bse = base;
        if (f) list[e * T_TOK + bse + woff + pos] = id;
        __syncthreads();
        if (tid == 0) base = bse + wsum[0] + wsum[1] + wsum[2] + wsum[3];
    }
    __syncthreads();
    int total = base;
    if (tid == 0) counts[e] = total;
    for (int i = total + tid; i < T_TOK; i += 256) list[e * T_TOK + i] = DUMP_ID;
}

// ---------------------------------------------------- grouped GEMM ----------
// MODE 0 (up):   A = xb gathered (row=id>>1, K=1024), B = w_up[e]  fp32 (2048 x K)
//                epilogue: h[id][n] = bf16( w2[id] * relu(v)^2 )
// MODE 1 (down): A = h gathered (row=id, K=2048),    B = w_down[e] fp32 (1024 x K)
//                epilogue: atomicAdd(out[id>>1][n], v)  -> K-SPLIT x2 is legal
// 128x128 tile, BK=64, DOUBLE-BUFFERED 1-barrier pipeline:
//   iter kt: issue loads(kt+1 -> buf^1) ; compute(buf) ; vmcnt-wait + B-write ;
//   barrier.  Load latency hides under the 32-MFMA compute phase.
template <int MODE>
__global__ __launch_bounds__(256, 2) void moe_gemm(
    const u16* __restrict__ Asrc, const int* __restrict__ list,
    const int* __restrict__ counts, const float* __restrict__ Ball32,
    const float* __restrict__ w2, u16* __restrict__ Hout,
    float* __restrict__ Cout) {
    constexpr int K   = (MODE == 0) ? DMODEL : HID;   // 1024 / 2048
    constexpr int N   = (MODE == 0) ? HID : DMODEL;   // 2048 / 1024
    constexpr int NKT = K / 64;                       // 16 / 32
    constexpr int NTN = N / 128;                      // 16 / 8
    constexpr int LOGNTN = (MODE == 0) ? 4 : 3;
    constexpr int KSP = (MODE == 0) ? 1 : 2;          // K-split (mode1: atomics)
    constexpr int KTPER = NKT / KSP;                  // 16 / 16

    const int b = blockIdx.x;
    const int e = b & 7;
    const int rest = b >> 3;
    const int n0 = (rest & (NTN - 1)) * 128;
    const int rest2 = rest >> LOGNTN;
    const int m0 = (rest2 & 15) * 128;
    const int ks = rest2 >> 4;                        // 0 for MODE 0
    if (m0 >= counts[e]) return;
    const int kt0 = ks * KTPER, kt1 = kt0 + KTPER;

    const int tid = threadIdx.x;
    const int lane = tid & 63;
    const int w = tid >> 6;

    __shared__ u16 As[2][128 * 64];
    __shared__ u16 Bs[2][128 * 64];

    const int* mylist = list + e * T_TOK + m0;
    const float* B32 = Ball32 + (size_t)e * HID * DMODEL;

    const u16* ap[4];
    const float4* bp[4];
    int bwr[4];
    const int c8 = tid & 7;                  // linear k-chunk this thread loads
#pragma unroll
    for (int it = 0; it < 4; ++it) {
        int row = it * 32 + (tid >> 3);
        int gs = c8 ^ (row & 7);
        int id = mylist[row];
        int arow = (MODE == 0) ? (id >> 1) : id;
        ap[it] = Asrc + (size_t)arow * K + gs * 8;            // pre-swizzled src
        bp[it] = (const float4*)(B32 + (size_t)(n0 + row) * K) + c8 * 2;
        bwr[it] = row * 64 + gs * 8;                          // swizzled LDS dst
    }

    const int wm = (w >> 1) * 64;
    const int wn = (w & 1) * 64;
    const int quad = lane >> 4;
    const int lrow = lane & 15;

    f32x4 acc[4][4];
#pragma unroll
    for (int i = 0; i < 4; ++i)
#pragma unroll
        for (int j = 0; j < 4; ++j) acc[i][j] = f32x4{0.f, 0.f, 0.f, 0.f};

    float4 bu[4][2];                         // in-flight fp32 B tile

    auto stageA = [&](int kt, int buf) {
#pragma unroll
        for (int it = 0; it < 4; ++it)
            gl2lds16(ap[it] + kt * 64, &As[buf][(it * 256 + w * 64) * 8]);
    };
    auto loadB = [&](int kt) {
#pragma unroll
        for (int it = 0; it < 4; ++it) {
            bu[it][0] = bp[it][kt * 16];
            bu[it][1] = bp[it][kt * 16 + 1];
        }
    };
    auto writeB = [&](int buf) {
#pragma unroll
        for (int it = 0; it < 4; ++it) {
            u16x8 o;
            o[0] = f2bf(bu[it][0].x); o[1] = f2bf(bu[it][0].y);
            o[2] = f2bf(bu[it][0].z); o[3] = f2bf(bu[it][0].w);
            o[4] = f2bf(bu[it][1].x); o[5] = f2bf(bu[it][1].y);
            o[6] = f2bf(bu[it][1].z); o[7] = f2bf(bu[it][1].w);
            *(u16x8*)&Bs[buf][bwr[it]] = o;
        }
    };
    auto compute = [&](int buf) {
#pragma unroll
        for (int s = 0; s < 2; ++s) {
            const int q = s * 4 + quad;
            bf16x8 af[4], bfr[4];
#pragma unroll
            for (int i = 0; i < 4; ++i) {
                int ra = wm + i * 16 + lrow;
                int rb = wn + i * 16 + lrow;
                af[i]  = *(const bf16x8*)&As[buf][ra * 64 + (q ^ (ra & 7)) * 8];
                bfr[i] = *(const bf16x8*)&Bs[buf][rb * 64 + (q ^ (rb & 7)) * 8];
            }
#pragma unroll
            for (int i = 0; i < 4; ++i)
#pragma unroll
                for (int j = 0; j < 4; ++j)
                    acc[i][j] = __builtin_amdgcn_mfma_f32_16x16x32_bf16(
                        af[i], bfr[j], acc[i][j], 0, 0, 0);
        }
    };

    // prologue: fill buffer 0 with K-tile kt0
    stageA(kt0, 0);
    loadB(kt0);
    writeB(0);                               // implicit vmcnt wait covers stageA too
    __syncthreads();

    for (int kt = kt0; kt < kt1; ++kt) {
        const int cur = (kt - kt0) & 1;
        const int nxt = cur ^ 1;
        const bool more = (kt + 1 < kt1);
        if (more) {
            stageA(kt + 1, nxt);             // async: next A -> LDS buf^1
            loadB(kt + 1);                   // async: next B -> regs
        }
        compute(cur);                        // 32 MFMA hide the load latency
        if (more) writeB(nxt);               // vmcnt wait lands AFTER compute
        __syncthreads();                     // one barrier per K-step
    }

    // epilogue: C/D mapping col = lane&15, row = (lane>>4)*4 + reg
#pragma unroll
    for (int i = 0; i < 4; ++i) {
        int mbase = wm + i * 16 + (lane >> 4) * 4;
        int ids[4];
        float ww[4];
#pragma unroll
        for (int r = 0; r < 4; ++r) {
            ids[r] = mylist[mbase + r];
            if (MODE == 0) ww[r] = w2[ids[r]];
        }
#pragma unroll
        for (int j = 0; j < 4; ++j) {
            int n = n0 + wn + j * 16 + (lane & 15);
#pragma unroll
            for (int r = 0; r < 4; ++r) {
                float v = acc[i][j][r];
                if (MODE == 0) {
                    v = (v > 0.f) ? v * v * ww[r] : 0.f;
                    Hout[(size_t)ids[r] * HID + n] = f2bf(v);
                } else {
                    if (ids[r] != DUMP_ID)
                        atomicAdd(&Cout[(size_t)(ids[r] >> 1) * DMODEL + n], v);
                }
            }
        }
    }
}

// ---------------------------------------------------------------------------
extern "C" void kernel_launch(void* const* d_in, const int* in_sizes, int n_in,
                              void* d_out, int out_size, void* d_ws, size_t ws_size,
                              hipStream_t stream) {
    const float* x      = (const float*)d_in[0];
    const float* gate_w = (const float*)d_in[1];
    const float* w_up   = (const float*)d_in[2];
    const float* w_down = (const float*)d_in[3];
    const float* bias   = (const float*)d_in[4];
    float* out = (float*)d_out;

    // workspace layout (16B aligned chunks)
    char* p = (char*)d_ws;
    int* counts = (int*)p;                 p += 256;
    int* list   = (int*)p;                 p += NEXP * T_TOK * 4;
    float* w2   = (float*)p;               p += 4104 * 4;
    unsigned int* selpack = (unsigned int*)p;  p += T_TOK * 4;
    u16* xb  = (u16*)p;  p += (size_t)(T_TOK + 1) * DMODEL * 2;
    u16* h   = (u16*)p;  p += (size_t)(2 * T_TOK + 1) * HID * 2;

    // 0. zero output (down-GEMM accumulates into it)
    hipMemsetAsync(d_out, 0, (size_t)out_size * sizeof(float), stream);

    // 1. router scores + x->bf16 + dump-row init
    fused_pre<<<257, 256, 0, stream>>>(
        (const float4*)x, (const float4*)gate_w, bias,
        (ushort4*)xb, selpack, w2,
        (unsigned int*)(xb + (size_t)T_TOK * DMODEL));

    // 2. deterministic list build (no global atomics)
    build_lists<<<NEXP, 256, 0, stream>>>(selpack, counts, list);

    // 3. up-GEMM: h = bf16( w2 * relu(x @ Wu^T)^2 ), Wu staged fp32->bf16 inline
    moe_gemm<0><<<16 * (HID / 128) * NEXP, 256, 0, stream>>>(
        xb, list, counts, w_up, w2, h, nullptr);

    // 4. down-GEMM + combine (K-split x2): out[t] += h[id] @ Wd^T
    moe_gemm<1><<<2 * 16 * (DMODEL / 128) * NEXP, 256, 0, stream>>>(
        h, list, counts, w_down, w2, nullptr, out);
}

// Round 6
// 258.353 us; speedup vs baseline: 1.0496x; 1.0496x over previous
//
#include <hip/hip_runtime.h>
#include <cstdint>
#include <cstddef>

#define T_TOK 2048
#define DMODEL 1024
#define NEXP 8
#define HID 2048
#define DUMP_ID 4096   // assignment-id for padding rows (token row 2048 = zeros)

typedef __bf16 bf16x8 __attribute__((ext_vector_type(8)));
typedef float f32x4 __attribute__((ext_vector_type(4)));
typedef unsigned short u16;
typedef u16 u16x8 __attribute__((ext_vector_type(8)));

__device__ __forceinline__ u16 f2bf(float f) {
    union { float f; unsigned int u; } v; v.f = f;
    unsigned int u = v.u;
    unsigned int r = (u + 0x7FFFu + ((u >> 16) & 1u)) >> 16;  // RNE
    return (u16)r;
}

__device__ __forceinline__ void gl2lds16(const void* g, void* l) {
    __builtin_amdgcn_global_load_lds(
        (const __attribute__((address_space(1))) void*)g,
        (__attribute__((address_space(3))) void*)l,
        16, 0, 0);
}

// ------------------------------------------------------------ fused_pre -----
// blocks [0, 256)  : router scores (one wave = 2 tokens, NO atomics) + x->bf16
// block  256       : zero xb dump row
__global__ __launch_bounds__(256) void fused_pre(
    const float4* __restrict__ x4, const float4* __restrict__ gw4,
    const float* __restrict__ bias, ushort4* __restrict__ xb4,
    unsigned int* __restrict__ selpack, float* __restrict__ w2,
    unsigned int* __restrict__ xb_dump_row_u32) {
    const int b = blockIdx.x;
    const int tid = threadIdx.x;

    if (b == 256) {                          // ---- zero dump token row ----
        if (tid < DMODEL / 2) xb_dump_row_u32[tid] = 0;
        return;
    }
    // ---- router: wave wv of router-block b handles tokens 2p, 2p+1 ----
    const int wv = tid >> 6;
    const int lane = tid & 63;
    const int pair = b * 4 + wv;             // 0..1023
    const int t0 = 2 * pair, t1 = t0 + 1;

    float acc0[NEXP], acc1[NEXP];
#pragma unroll
    for (int e = 0; e < NEXP; ++e) { acc0[e] = 0.f; acc1[e] = 0.f; }
#pragma unroll
    for (int j = 0; j < 4; ++j) {
        int i4 = lane + j * 64;              // float4 index within row (256/row)
        float4 a0 = x4[t0 * 256 + i4];
        float4 a1 = x4[t1 * 256 + i4];
        ushort4 s0, s1;
        s0.x = f2bf(a0.x); s0.y = f2bf(a0.y); s0.z = f2bf(a0.z); s0.w = f2bf(a0.w);
        s1.x = f2bf(a1.x); s1.y = f2bf(a1.y); s1.z = f2bf(a1.z); s1.w = f2bf(a1.w);
        xb4[t0 * 256 + i4] = s0;
        xb4[t1 * 256 + i4] = s1;
#pragma unroll
        for (int e = 0; e < NEXP; ++e) {
            float4 g = gw4[e * 256 + i4];
            acc0[e] += a0.x * g.x + a0.y * g.y + a0.z * g.z + a0.w * g.w;
            acc1[e] += a1.x * g.x + a1.y * g.y + a1.z * g.z + a1.w * g.w;
        }
    }
#pragma unroll
    for (int e = 0; e < NEXP; ++e)
        for (int off = 32; off > 0; off >>= 1) {
            acc0[e] += __shfl_xor(acc0[e], off, 64);
            acc1[e] += __shfl_xor(acc1[e], off, 64);
        }
    if (lane == 0) {
#pragma unroll
        for (int tt = 0; tt < 2; ++tt) {
            int t = tt ? t1 : t0;
            float sc[NEXP], bi[NEXP];
#pragma unroll
            for (int e = 0; e < NEXP; ++e) {
                float a = tt ? acc1[e] : acc0[e];
                sc[e] = 1.f / (1.f + expf(-a));
                bi[e] = sc[e] + bias[e];
            }
            int e0 = 0;
            for (int e = 1; e < NEXP; ++e) if (bi[e] > bi[e0]) e0 = e;  // ties->lowest
            int e1 = -1;
            for (int e = 0; e < NEXP; ++e) {
                if (e == e0) continue;
                if (e1 < 0 || bi[e] > bi[e1]) e1 = e;
            }
            selpack[t] = (unsigned int)e0 | ((unsigned int)e1 << 8);
            w2[2 * t]     = sc[e0] * sc[e0];
            w2[2 * t + 1] = sc[e1] * sc[e1];
        }
    }
}

// ------------------------------------------------------------ build_lists ---
// 8 blocks (one per expert), 256 threads: deterministic ballot-compaction.
__global__ __launch_bounds__(256) void build_lists(
    const unsigned int* __restrict__ selpack, int* __restrict__ counts,
    int* __restrict__ list) {
    const int e = blockIdx.x;
    const int tid = threadIdx.x;
    const int lane = tid & 63;
    const int wv = tid >> 6;
    __shared__ int wsum[4];
    __shared__ int base;
    if (tid == 0) base = 0;
    __syncthreads();
    for (int tb = 0; tb < T_TOK; tb += 256) {
        int t = tb + tid;
        unsigned int sp = selpack[t];
        bool f1 = ((sp >> 8) & 255u) == (unsigned)e;
        bool f = ((sp & 255u) == (unsigned)e) | f1;
        int id = 2 * t + (f1 ? 1 : 0);
        unsigned long long m = __ballot(f);
        int pos = __popcll(m & ((1ull << lane) - 1ull));
        if (lane == 0) wsum[wv] = __popcll(m);
        __syncthreads();
        int woff = 0;
#pragma unroll
        for (int i = 0; i < 4; ++i) if (i < wv) woff += wsum[i];
        int bse = base;
        if (f) list[e * T_TOK + bse + woff + pos] = id;
        __syncthreads();
        if (tid == 0) base = bse + wsum[0] + wsum[1] + wsum[2] + wsum[3];
    }
    __syncthreads();
    int total = base;
    if (tid == 0) counts[e] = total;
    for (int i = total + tid; i < T_TOK; i += 256) list[e * T_TOK + i] = DUMP_ID;
}

// ---------------------------------------------------- grouped GEMM ----------
// 256x128 tile, BK=64, 512 threads (8 waves as 4m x 2n, 64x64 per wave).
// Grid = 1024 = 8 experts x 128 blocks; bijective XCD swizzle pins each
// expert to one XCD so its weight slice (512/256 KB per K-step) is served
// from that XCD's L2 across all re-reads.
// A: double-buffered gl2lds (linear dest, pre-swizzled source), issued
//    BEFORE compute so the barrier's vmcnt(0) drain lands post-compute.
// B: fp32 reg-stage -> RNE cvt -> XOR-swizzled ds_write (single buffer).
// MODE 0 (up):   A = xb gathered (row=id>>1, K=1024), B = w_up[e]   (2048 x K)
//                epilogue: h[id][n] = bf16( w2[id] * relu(v)^2 )
// MODE 1 (down): A = h gathered (row=id, K=2048),    B = w_down[e]  (1024 x K)
//                K-split x2; epilogue: atomicAdd(out[id>>1][n], v)
template <int MODE>
__global__ __launch_bounds__(512, 2) void moe_gemm(
    const u16* __restrict__ Asrc, const int* __restrict__ list,
    const int* __restrict__ counts, const float* __restrict__ Ball32,
    const float* __restrict__ w2, u16* __restrict__ Hout,
    float* __restrict__ Cout) {
    constexpr int K   = (MODE == 0) ? DMODEL : HID;   // 1024 / 2048
    constexpr int N   = (MODE == 0) ? HID : DMODEL;   // 2048 / 1024
    constexpr int NKT = K / 64;                       // 16 / 32
    constexpr int NTN = N / 128;                      // 16 / 8
    constexpr int LOGNTN = (MODE == 0) ? 4 : 3;
    constexpr int KSP = (MODE == 0) ? 1 : 2;          // K-split (mode1: atomics)
    constexpr int KTPER = NKT / KSP;                  // 16 / 16

    // bijective XCD swizzle (nwg=1024, nwg%8==0): XCD x -> wg in [x*128,(x+1)*128)
    const int wg = ((int)blockIdx.x & 7) * ((int)gridDim.x >> 3) + ((int)blockIdx.x >> 3);
    const int e  = wg >> 7;                           // expert = XCD
    const int r  = wg & 127;
    const int n0 = (r & (NTN - 1)) * 128;
    const int mi = (r >> LOGNTN) & 7;
    const int ks = r >> (LOGNTN + 3);                 // 0 for MODE 0
    const int m0 = mi * 256;
    if (m0 >= counts[e]) return;
    const int kt0 = ks * KTPER, kt1 = kt0 + KTPER;

    const int tid = threadIdx.x;
    const int lane = tid & 63;
    const int w = tid >> 6;

    __shared__ u16 As[2][256 * 64];                   // 64 KB (double-buffered)
    __shared__ u16 Bs[128 * 64];                      // 16 KB

    const int* mylist = list + e * T_TOK + m0;
    const float* B32 = Ball32 + (size_t)e * HID * DMODEL;

    const u16* ap[4];
    const float4* bp[2];
    int bwr[2];
    const int c8 = tid & 7;                           // linear k-chunk of thread
#pragma unroll
    for (int it = 0; it < 4; ++it) {                  // A: 256 rows, 4 per thread
        int row = it * 64 + (tid >> 3);
        int gs = c8 ^ (row & 7);
        int id = mylist[row];
        int arow = (MODE == 0) ? (id >> 1) : id;
        ap[it] = Asrc + (size_t)arow * K + gs * 8;    // pre-swizzled source
    }
#pragma unroll
    for (int it = 0; it < 2; ++it) {                  // B: 128 rows, 2 per thread
        int row = it * 64 + (tid >> 3);
        int gs = c8 ^ (row & 7);
        bp[it] = (const float4*)(B32 + (size_t)(n0 + row) * K) + c8 * 2;
        bwr[it] = row * 64 + gs * 8;                  // swizzled LDS slot
    }

    const int wm = (w >> 1) * 64;                     // 4 m-waves
    const int wn = (w & 1) * 64;                      // 2 n-waves
    const int quad = lane >> 4;
    const int lrow = lane & 15;

    f32x4 acc[4][4];
#pragma unroll
    for (int i = 0; i < 4; ++i)
#pragma unroll
        for (int j = 0; j < 4; ++j) acc[i][j] = f32x4{0.f, 0.f, 0.f, 0.f};

    float4 bu[2][2];                                  // in-flight fp32 B tile

    auto stageA = [&](int kt, int buf) {
#pragma unroll
        for (int it = 0; it < 4; ++it)
            gl2lds16(ap[it] + kt * 64, &As[buf][(it * 64 + w * 8) * 64]);
    };
    auto loadB = [&](int kt) {
#pragma unroll
        for (int it = 0; it < 2; ++it) {
            bu[it][0] = bp[it][kt * 16];
            bu[it][1] = bp[it][kt * 16 + 1];
        }
    };
    auto writeB = [&]() {
#pragma unroll
        for (int it = 0; it < 2; ++it) {
            u16x8 o;
            o[0] = f2bf(bu[it][0].x); o[1] = f2bf(bu[it][0].y);
            o[2] = f2bf(bu[it][0].z); o[3] = f2bf(bu[it][0].w);
            o[4] = f2bf(bu[it][1].x); o[5] = f2bf(bu[it][1].y);
            o[6] = f2bf(bu[it][1].z); o[7] = f2bf(bu[it][1].w);
            *(u16x8*)&Bs[bwr[it]] = o;
        }
    };
    auto compute = [&](int buf) {
#pragma unroll
        for (int s = 0; s < 2; ++s) {
            const int q = s * 4 + quad;
            bf16x8 af[4], bfr[4];
#pragma unroll
            for (int i = 0; i < 4; ++i) {
                int ra = wm + i * 16 + lrow;
                int rb = wn + i * 16 + lrow;
                af[i]  = *(const bf16x8*)&As[buf][ra * 64 + (q ^ (ra & 7)) * 8];
                bfr[i] = *(const bf16x8*)&Bs[rb * 64 + (q ^ (rb & 7)) * 8];
            }
#pragma unroll
            for (int i = 0; i < 4; ++i)
#pragma unroll
                for (int j = 0; j < 4; ++j)
                    acc[i][j] = __builtin_amdgcn_mfma_f32_16x16x32_bf16(
                        af[i], bfr[j], acc[i][j], 0, 0, 0);
        }
    };

    // prologue: tile kt0 -> As[0] (async) + Bs (via regs)
    loadB(kt0);
    stageA(kt0, 0);
    writeB();                    // counted vmcnt wait on B regs
    __syncthreads();             // full drain (once) — As[0] + Bs ready

    int cur = 0;
    for (int kt = kt0; kt < kt1; ++kt) {
        const bool more = (kt + 1 < kt1);
        if (more) {
            loadB(kt + 1);       // B(kt+1) -> regs, flies across compute
            stageA(kt + 1, cur ^ 1);  // A(kt+1) -> other LDS buf, flies too
        }
        compute(cur);            // 32 MFMA/wave on As[cur] + Bs
        __syncthreads();         // barrier 1: readers done; vmcnt(0) drain here
                                 // covers loads issued BEFORE compute -> cheap
        if (more) {
            writeB();            // Bs <- tile kt+1 (B regs already drained)
            __syncthreads();     // barrier 2: Bs visible (lgkm only, cheap)
            cur ^= 1;
        }
    }

    // epilogue: C/D mapping col = lane&15, row = (lane>>4)*4 + reg
#pragma unroll
    for (int i = 0; i < 4; ++i) {
        int mbase = wm + i * 16 + (lane >> 4) * 4;
        int ids[4];
        float ww[4];
#pragma unroll
        for (int rr = 0; rr < 4; ++rr) {
            ids[rr] = mylist[mbase + rr];
            if (MODE == 0) ww[rr] = w2[ids[rr]];
        }
#pragma unroll
        for (int j = 0; j < 4; ++j) {
            int n = n0 + wn + j * 16 + (lane & 15);
#pragma unroll
            for (int rr = 0; rr < 4; ++rr) {
                float v = acc[i][j][rr];
                if (MODE == 0) {
                    v = (v > 0.f) ? v * v * ww[rr] : 0.f;
                    Hout[(size_t)ids[rr] * HID + n] = f2bf(v);
                } else {
                    if (ids[rr] != DUMP_ID)
                        atomicAdd(&Cout[(size_t)(ids[rr] >> 1) * DMODEL + n], v);
                }
            }
        }
    }
}

// ---------------------------------------------------------------------------
extern "C" void kernel_launch(void* const* d_in, const int* in_sizes, int n_in,
                              void* d_out, int out_size, void* d_ws, size_t ws_size,
                              hipStream_t stream) {
    const float* x      = (const float*)d_in[0];
    const float* gate_w = (const float*)d_in[1];
    const float* w_up   = (const float*)d_in[2];
    const float* w_down = (const float*)d_in[3];
    const float* bias   = (const float*)d_in[4];
    float* out = (float*)d_out;

    // workspace layout (16B aligned chunks)
    char* p = (char*)d_ws;
    int* counts = (int*)p;                 p += 256;
    int* list   = (int*)p;                 p += NEXP * T_TOK * 4;
    float* w2   = (float*)p;               p += 4104 * 4;
    unsigned int* selpack = (unsigned int*)p;  p += T_TOK * 4;
    u16* xb  = (u16*)p;  p += (size_t)(T_TOK + 1) * DMODEL * 2;
    u16* h   = (u16*)p;  p += (size_t)(2 * T_TOK + 1) * HID * 2;

    // 0. zero output (down-GEMM accumulates into it)
    hipMemsetAsync(d_out, 0, (size_t)out_size * sizeof(float), stream);

    // 1. router scores + x->bf16 + dump-row init
    fused_pre<<<257, 256, 0, stream>>>(
        (const float4*)x, (const float4*)gate_w, bias,
        (ushort4*)xb, selpack, w2,
        (unsigned int*)(xb + (size_t)T_TOK * DMODEL));

    // 2. deterministic list build (no global atomics)
    build_lists<<<NEXP, 256, 0, stream>>>(selpack, counts, list);

    // 3. up-GEMM: h = bf16( w2 * relu(x @ Wu^T)^2 )   (1024 blocks, 512 thr)
    moe_gemm<0><<<NEXP * 128, 512, 0, stream>>>(
        xb, list, counts, w_up, w2, h, nullptr);

    // 4. down-GEMM + combine (K-split x2): out[t] += h[id] @ Wd^T
    moe_gemm<1><<<NEXP * 128, 512, 0, stream>>>(
        h, list, counts, w_down, w2, nullptr, out);
}

// Round 7
// 255.034 us; speedup vs baseline: 1.0633x; 1.0130x over previous
//
#include <hip/hip_runtime.h>
#include <cstdint>
#include <cstddef>

#define T_TOK 2048
#define DMODEL 1024
#define NEXP 8
#define HID 2048
#define DUMP_ID 4096   // assignment-id for padding rows (token row 2048 = zeros)

typedef __bf16 bf16x8 __attribute__((ext_vector_type(8)));
typedef float f32x4 __attribute__((ext_vector_type(4)));
typedef unsigned short u16;
typedef u16 u16x8 __attribute__((ext_vector_type(8)));

__device__ __forceinline__ u16 f2bf(float f) {
    union { float f; unsigned int u; } v; v.f = f;
    unsigned int u = v.u;
    unsigned int r = (u + 0x7FFFu + ((u >> 16) & 1u)) >> 16;  // RNE
    return (u16)r;
}

__device__ __forceinline__ void gl2lds16(const void* g, void* l) {
    __builtin_amdgcn_global_load_lds(
        (const __attribute__((address_space(1))) void*)g,
        (__attribute__((address_space(3))) void*)l,
        16, 0, 0);
}

// ------------------------------------------------------------ fused_pre -----
// blocks [0, 256)  : router scores (one wave = 2 tokens, NO atomics) + x->bf16
// block  256       : zero xb dump row
__global__ __launch_bounds__(256) void fused_pre(
    const float4* __restrict__ x4, const float4* __restrict__ gw4,
    const float* __restrict__ bias, ushort4* __restrict__ xb4,
    unsigned int* __restrict__ selpack, float* __restrict__ w2,
    unsigned int* __restrict__ xb_dump_row_u32) {
    const int b = blockIdx.x;
    const int tid = threadIdx.x;

    if (b == 256) {                          // ---- zero dump token row ----
        if (tid < DMODEL / 2) xb_dump_row_u32[tid] = 0;
        return;
    }
    // ---- router: wave wv of router-block b handles tokens 2p, 2p+1 ----
    const int wv = tid >> 6;
    const int lane = tid & 63;
    const int pair = b * 4 + wv;             // 0..1023
    const int t0 = 2 * pair, t1 = t0 + 1;

    float acc0[NEXP], acc1[NEXP];
#pragma unroll
    for (int e = 0; e < NEXP; ++e) { acc0[e] = 0.f; acc1[e] = 0.f; }
#pragma unroll
    for (int j = 0; j < 4; ++j) {
        int i4 = lane + j * 64;              // float4 index within row (256/row)
        float4 a0 = x4[t0 * 256 + i4];
        float4 a1 = x4[t1 * 256 + i4];
        ushort4 s0, s1;
        s0.x = f2bf(a0.x); s0.y = f2bf(a0.y); s0.z = f2bf(a0.z); s0.w = f2bf(a0.w);
        s1.x = f2bf(a1.x); s1.y = f2bf(a1.y); s1.z = f2bf(a1.z); s1.w = f2bf(a1.w);
        xb4[t0 * 256 + i4] = s0;
        xb4[t1 * 256 + i4] = s1;
#pragma unroll
        for (int e = 0; e < NEXP; ++e) {
            float4 g = gw4[e * 256 + i4];
            acc0[e] += a0.x * g.x + a0.y * g.y + a0.z * g.z + a0.w * g.w;
            acc1[e] += a1.x * g.x + a1.y * g.y + a1.z * g.z + a1.w * g.w;
        }
    }
#pragma unroll
    for (int e = 0; e < NEXP; ++e)
        for (int off = 32; off > 0; off >>= 1) {
            acc0[e] += __shfl_xor(acc0[e], off, 64);
            acc1[e] += __shfl_xor(acc1[e], off, 64);
        }
    if (lane == 0) {
#pragma unroll
        for (int tt = 0; tt < 2; ++tt) {
            int t = tt ? t1 : t0;
            float sc[NEXP], bi[NEXP];
#pragma unroll
            for (int e = 0; e < NEXP; ++e) {
                float a = tt ? acc1[e] : acc0[e];
                sc[e] = 1.f / (1.f + expf(-a));
                bi[e] = sc[e] + bias[e];
            }
            int e0 = 0;
            for (int e = 1; e < NEXP; ++e) if (bi[e] > bi[e0]) e0 = e;  // ties->lowest
            int e1 = -1;
            for (int e = 0; e < NEXP; ++e) {
                if (e == e0) continue;
                if (e1 < 0 || bi[e] > bi[e1]) e1 = e;
            }
            selpack[t] = (unsigned int)e0 | ((unsigned int)e1 << 8);
            w2[2 * t]     = sc[e0] * sc[e0];
            w2[2 * t + 1] = sc[e1] * sc[e1];
        }
    }
}

// ------------------------------------------------------------ build_lists ---
// 8 blocks (one per expert), 256 threads: deterministic ballot-compaction.
__global__ __launch_bounds__(256) void build_lists(
    const unsigned int* __restrict__ selpack, int* __restrict__ counts,
    int* __restrict__ list) {
    const int e = blockIdx.x;
    const int tid = threadIdx.x;
    const int lane = tid & 63;
    const int wv = tid >> 6;
    __shared__ int wsum[4];
    __shared__ int base;
    if (tid == 0) base = 0;
    __syncthreads();
    for (int tb = 0; tb < T_TOK; tb += 256) {
        int t = tb + tid;
        unsigned int sp = selpack[t];
        bool f1 = ((sp >> 8) & 255u) == (unsigned)e;
        bool f = ((sp & 255u) == (unsigned)e) | f1;
        int id = 2 * t + (f1 ? 1 : 0);
        unsigned long long m = __ballot(f);
        int pos = __popcll(m & ((1ull << lane) - 1ull));
        if (lane == 0) wsum[wv] = __popcll(m);
        __syncthreads();
        int woff = 0;
#pragma unroll
        for (int i = 0; i < 4; ++i) if (i < wv) woff += wsum[i];
        int bse = base;
        if (f) list[e * T_TOK + bse + woff + pos] = id;
        __syncthreads();
        if (tid == 0) base = bse + wsum[0] + wsum[1] + wsum[2] + wsum[3];
    }
    __syncthreads();
    int total = base;
    if (tid == 0) counts[e] = total;
    for (int i = total + tid; i < T_TOK; i += 256) list[e * T_TOK + i] = DUMP_ID;
}

// ---------------------------------------------------- grouped GEMM ----------
// Round-4 proven inner loop (128x128, BK=64, 256 thr, single-buffer).
// MODE 0 (up):   A = xb gathered (row=id>>1, K=1024), B = w_up[e] fp32
//                epilogue: h[e*T + m0 + row][n] = bf16( w2[id]*relu(v)^2 )
//                (h stored in LIST-POSITION order -> down-GEMM reads A
//                 contiguously, no gather)
// MODE 1 (down): A = h (positions e*T+m0.., K=2048, CONTIGUOUS),
//                B = w_down[e] fp32
//                epilogue: part[id][n] = v   (plain store, ids unique ->
//                NO atomics; combine kernel sums the 2 slots per token)
// A: gl2lds, linear LDS dest, XOR-pre-swizzled global source.
// B: fp32 reg-stage -> RNE cvt -> XOR-swizzled ds_write.
template <int MODE>
__global__ __launch_bounds__(256, 2) void moe_gemm(
    const u16* __restrict__ Asrc, const int* __restrict__ list,
    const int* __restrict__ counts, const float* __restrict__ Ball32,
    const float* __restrict__ w2, u16* __restrict__ Hout,
    float* __restrict__ Pout) {
    constexpr int K   = (MODE == 0) ? DMODEL : HID;   // 1024 / 2048
    constexpr int NKT = K / 64;                       // 16 / 32
    constexpr int NTN = ((MODE == 0) ? HID : DMODEL) / 128;  // 16 / 8
    constexpr int LOGNTN = (MODE == 0) ? 4 : 3;

    const int b = blockIdx.x;
    const int e = b & 7;                              // expert == XCD (b%8)
    const int rest = b >> 3;
    const int m0 = (rest >> LOGNTN) * 128;
    if (m0 >= counts[e]) return;
    const int n0 = (rest & (NTN - 1)) * 128;

    const int tid = threadIdx.x;
    const int lane = tid & 63;
    const int w = tid >> 6;

    __shared__ u16 As[128 * 64];
    __shared__ u16 Bs[128 * 64];

    const int* mylist = list + e * T_TOK + m0;
    const float* B32 = Ball32 + (size_t)e * HID * DMODEL;

    const u16* ap[4];
    const float4* bp[4];
    int bwr[4];
    const int c8 = tid & 7;                  // linear k-chunk this thread loads
#pragma unroll
    for (int it = 0; it < 4; ++it) {
        int row = it * 32 + (tid >> 3);
        int gs = c8 ^ (row & 7);
        if (MODE == 0) {
            int id = mylist[row];
            ap[it] = Asrc + (size_t)(id >> 1) * K + gs * 8;   // gathered tokens
        } else {
            ap[it] = Asrc + (size_t)(e * T_TOK + m0 + row) * K + gs * 8;  // contiguous
        }
        bp[it] = (const float4*)(B32 + (size_t)(n0 + row) * K) + c8 * 2;
        bwr[it] = row * 64 + gs * 8;                          // swizzled LDS dst
    }

    const int wm = (w >> 1) * 64;
    const int wn = (w & 1) * 64;
    const int quad = lane >> 4;
    const int lrow = lane & 15;

    f32x4 acc[4][4];
#pragma unroll
    for (int i = 0; i < 4; ++i)
#pragma unroll
        for (int j = 0; j < 4; ++j) acc[i][j] = f32x4{0.f, 0.f, 0.f, 0.f};

    for (int kt = 0; kt < NKT; ++kt) {
        // A: async global->LDS (linear dest, pre-swizzled global source)
#pragma unroll
        for (int it = 0; it < 4; ++it)
            gl2lds16(ap[it] + kt * 64, &As[(it * 256 + w * 64) * 8]);
        // B: fp32 reg-stage (8 independent dwordx4), cvt, swizzled ds_write
        float4 bu[4][2];
#pragma unroll
        for (int it = 0; it < 4; ++it) {
            bu[it][0] = bp[it][kt * 16];
            bu[it][1] = bp[it][kt * 16 + 1];
        }
#pragma unroll
        for (int it = 0; it < 4; ++it) {
            u16x8 o;
            o[0] = f2bf(bu[it][0].x); o[1] = f2bf(bu[it][0].y);
            o[2] = f2bf(bu[it][0].z); o[3] = f2bf(bu[it][0].w);
            o[4] = f2bf(bu[it][1].x); o[5] = f2bf(bu[it][1].y);
            o[6] = f2bf(bu[it][1].z); o[7] = f2bf(bu[it][1].w);
            *(u16x8*)&Bs[bwr[it]] = o;
        }
        __syncthreads();  // drain staging
#pragma unroll
        for (int s = 0; s < 2; ++s) {
            const int q = s * 4 + quad;
            bf16x8 af[4], bfr[4];
#pragma unroll
            for (int i = 0; i < 4; ++i) {
                int ra = wm + i * 16 + lrow;
                int rb = wn + i * 16 + lrow;
                af[i]  = *(const bf16x8*)&As[ra * 64 + (q ^ (ra & 7)) * 8];
                bfr[i] = *(const bf16x8*)&Bs[rb * 64 + (q ^ (rb & 7)) * 8];
            }
#pragma unroll
            for (int i = 0; i < 4; ++i)
#pragma unroll
                for (int j = 0; j < 4; ++j)
                    acc[i][j] = __builtin_amdgcn_mfma_f32_16x16x32_bf16(
                        af[i], bfr[j], acc[i][j], 0, 0, 0);
        }
        __syncthreads();  // protect LDS before next stage
    }

    // epilogue: C/D mapping col = lane&15, row = (lane>>4)*4 + reg
#pragma unroll
    for (int i = 0; i < 4; ++i) {
        int mbase = wm + i * 16 + (lane >> 4) * 4;
        int ids[4];
        float ww[4];
#pragma unroll
        for (int r = 0; r < 4; ++r) {
            ids[r] = mylist[mbase + r];
            if (MODE == 0) ww[r] = w2[ids[r]];
        }
#pragma unroll
        for (int j = 0; j < 4; ++j) {
            int n = n0 + wn + j * 16 + (lane & 15);
#pragma unroll
            for (int r = 0; r < 4; ++r) {
                float v = acc[i][j][r];
                if (MODE == 0) {
                    v = (v > 0.f) ? v * v * ww[r] : 0.f;   // pad rows: v==0 -> 0
                    Hout[(size_t)(e * T_TOK + m0 + mbase + r) * HID + n] = f2bf(v);
                } else {
                    if (ids[r] != DUMP_ID)
                        Pout[(size_t)ids[r] * DMODEL + n] = v;   // plain store
                }
            }
        }
    }
}

// ------------------------------------------------------------ combine -------
// out[t] = part[2t] + part[2t+1]   (2048 blocks x 256 thr x float4)
__global__ __launch_bounds__(256) void combine(
    const float4* __restrict__ part4, float4* __restrict__ out4) {
    int idx = blockIdx.x * 256 + threadIdx.x;     // [0, 524288)
    int t = idx >> 8;
    int d4 = idx & 255;
    float4 p0 = part4[(size_t)(2 * t) * 256 + d4];
    float4 p1 = part4[(size_t)(2 * t + 1) * 256 + d4];
    float4 o;
    o.x = p0.x + p1.x; o.y = p0.y + p1.y;
    o.z = p0.z + p1.z; o.w = p0.w + p1.w;
    out4[idx] = o;
}

// ---------------------------------------------------------------------------
extern "C" void kernel_launch(void* const* d_in, const int* in_sizes, int n_in,
                              void* d_out, int out_size, void* d_ws, size_t ws_size,
                              hipStream_t stream) {
    const float* x      = (const float*)d_in[0];
    const float* gate_w = (const float*)d_in[1];
    const float* w_up   = (const float*)d_in[2];
    const float* w_down = (const float*)d_in[3];
    const float* bias   = (const float*)d_in[4];
    float* out = (float*)d_out;

    // workspace layout (16B aligned chunks)
    char* p = (char*)d_ws;
    int* counts = (int*)p;                 p += 256;
    int* list   = (int*)p;                 p += NEXP * T_TOK * 4;
    float* w2   = (float*)p;               p += 4104 * 4;
    unsigned int* selpack = (unsigned int*)p;  p += T_TOK * 4;
    u16* xb  = (u16*)p;  p += (size_t)(T_TOK + 1) * DMODEL * 2;          // ~4 MB
    u16* h   = (u16*)p;  p += (size_t)NEXP * T_TOK * HID * 2;            // 64 MB
    float* part = (float*)p;  p += (size_t)2 * T_TOK * DMODEL * 4;       // 16 MB

    // 1. router scores + x->bf16 + dump-row init  (no output memset needed)
    fused_pre<<<257, 256, 0, stream>>>(
        (const float4*)x, (const float4*)gate_w, bias,
        (ushort4*)xb, selpack, w2,
        (unsigned int*)(xb + (size_t)T_TOK * DMODEL));

    // 2. deterministic list build (no global atomics)
    build_lists<<<NEXP, 256, 0, stream>>>(selpack, counts, list);

    // 3. up-GEMM: h(position-order) = bf16( w2 * relu(x @ Wu^T)^2 )
    moe_gemm<0><<<16 * (HID / 128) * NEXP, 256, 0, stream>>>(
        xb, list, counts, w_up, w2, h, nullptr);

    // 4. down-GEMM: part[id] = h_row @ Wd^T   (plain stores, no atomics)
    moe_gemm<1><<<16 * (DMODEL / 128) * NEXP, 256, 0, stream>>>(
        h, list, counts, w_down, w2, nullptr, part);

    // 5. combine: out[t] = part[2t] + part[2t+1]
    combine<<<T_TOK * DMODEL / 4 / 256, 256, 0, stream>>>(
        (const float4*)part, (float4*)out);
}